// Round 2
// baseline (559.161 us; speedup 1.0000x reference)
//
#include <hip/hip_runtime.h>
#include <hip/hip_bf16.h>
#include <math.h>

#define T_TOK 8192
#define D_DIM 2048
#define H_DIM 2048
#define E_NUM 8
#define CAP   2048

typedef __attribute__((ext_vector_type(4))) float f32x4;
typedef __attribute__((ext_vector_type(8))) __bf16 bf16x8;

__device__ __forceinline__ unsigned short f2bf(float f) {
  unsigned int u = __float_as_uint(f);
  return (unsigned short)((u + 0x7FFFu + ((u >> 16) & 1u)) >> 16);
}

__device__ __forceinline__ void async_load16(const void* g, void* l) {
  __builtin_amdgcn_global_load_lds(
      (const __attribute__((address_space(1))) void*)g,
      (__attribute__((address_space(3))) void*)l, 16, 0, 0);
}

// ---- fused prep: w1cast (blocks 0..8191) + gate (8192..10239) +
//      w2sum (10240..14335) + b2sum (14336..14337) + init (14338) ----
// R1 change: all streaming phases rewritten load-all-then-process so the
// independent global loads are hoisted into registers (VGPR 44 was
// serializing them -> latency-bound at 25% of achievable HBM BW).
#define PREP_W1_BLOCKS 8192
#define PREP_GATE_BLOCKS 2048
#define PREP_W2_BLOCKS 4096
#define PREP_TOTAL (PREP_W1_BLOCKS + PREP_GATE_BLOCKS + PREP_W2_BLOCKS + 3)

__global__ __launch_bounds__(256) void prep_kernel(
    const float* __restrict__ x, const float* __restrict__ wg,
    const float* __restrict__ w1, const float* __restrict__ w2,
    const float* __restrict__ b2,
    unsigned short* __restrict__ xbf, int* __restrict__ topidx,
    float* __restrict__ gates, unsigned short* __restrict__ w1t,
    float* __restrict__ w2s, float* __restrict__ b2sum,
    int* __restrict__ slot_token, float* __restrict__ s_out)
{
  __shared__ unsigned short tile[64][68];
  int b = blockIdx.x;
  int tid = threadIdx.x;

  if (b < PREP_W1_BLOCKS) {
    // ---- W1 [E][D][H] fp32 -> W1T [E][H][D] bf16, 64x64 LDS transpose ----
    int e = b >> 10;
    int rem = b & 1023;
    int dt = rem >> 5, ht = rem & 31;
    const float* ibase = w1 + ((size_t)e * D_DIM + dt * 64) * H_DIM + ht * 64;
    int c4 = tid & 15, r0 = tid >> 4;
    // batch all 4 independent loads first (latency overlap)
    float4 v[4];
#pragma unroll
    for (int p = 0; p < 4; ++p)
      v[p] = *(const float4*)(ibase + (size_t)(r0 + p * 16) * H_DIM + c4 * 4);
#pragma unroll
    for (int p = 0; p < 4; ++p) {
      int r = r0 + p * 16;
      tile[r][c4 * 4 + 0] = f2bf(v[p].x);
      tile[r][c4 * 4 + 1] = f2bf(v[p].y);
      tile[r][c4 * 4 + 2] = f2bf(v[p].z);
      tile[r][c4 * 4 + 3] = f2bf(v[p].w);
    }
    __syncthreads();
    unsigned short* obase = w1t + ((size_t)e * H_DIM + ht * 64) * D_DIM + dt * 64;
    int dq = tid & 7, h0 = tid >> 3;
    // batch all LDS reads, then pack, then both stores
    unsigned int lo[2][4], hi[2][4];
#pragma unroll
    for (int p = 0; p < 2; ++p) {
      int hh = h0 + p * 32;
#pragma unroll
      for (int u = 0; u < 4; ++u) {
        lo[p][u] = tile[dq * 8 + u * 2][hh];
        hi[p][u] = tile[dq * 8 + u * 2 + 1][hh];
      }
    }
#pragma unroll
    for (int p = 0; p < 2; ++p) {
      int hh = h0 + p * 32;
      uint4 ov = make_uint4(lo[p][0] | (hi[p][0] << 16), lo[p][1] | (hi[p][1] << 16),
                            lo[p][2] | (hi[p][2] << 16), lo[p][3] | (hi[p][3] << 16));
      *(uint4*)(obase + (size_t)hh * D_DIM + dq * 8) = ov;
    }
  } else if (b < PREP_W1_BLOCKS + PREP_GATE_BLOCKS) {
    // ---- gating (fp32 logits, top-2, softmax gates) + x -> bf16 cast ----
    int bx = b - PREP_W1_BLOCKS;
    int w = tid >> 6, lane = tid & 63;
    int t = bx * 4 + w;
    const float4* xr = (const float4*)(x + (size_t)t * D_DIM);
    ushort4* xo = (ushort4*)(xbf + (size_t)t * D_DIM);
    // batch all 8 independent row loads first
    float4 v[8];
#pragma unroll
    for (int it = 0; it < 8; ++it) v[it] = xr[it * 64 + lane];
    float acc[8];
#pragma unroll
    for (int e = 0; e < 8; ++e) acc[e] = 0.f;
#pragma unroll
    for (int it = 0; it < 8; ++it) {
      int i4 = it * 64 + lane;
      int d = i4 * 4;
      float xv[4] = {v[it].x, v[it].y, v[it].z, v[it].w};
#pragma unroll
      for (int u = 0; u < 4; ++u) {
        const float4* wr = (const float4*)(wg + (size_t)(d + u) * 8);
        float4 w01 = wr[0], w23 = wr[1];
        acc[0] += xv[u] * w01.x; acc[1] += xv[u] * w01.y;
        acc[2] += xv[u] * w01.z; acc[3] += xv[u] * w01.w;
        acc[4] += xv[u] * w23.x; acc[5] += xv[u] * w23.y;
        acc[6] += xv[u] * w23.z; acc[7] += xv[u] * w23.w;
      }
      ushort4 o;
      o.x = f2bf(v[it].x); o.y = f2bf(v[it].y); o.z = f2bf(v[it].z); o.w = f2bf(v[it].w);
      xo[i4] = o;
    }
#pragma unroll
    for (int off = 1; off < 64; off <<= 1) {
#pragma unroll
      for (int e = 0; e < 8; ++e) acc[e] += __shfl_xor(acc[e], off);
    }
    if (lane == 0) {
      int e1 = 0; float l1 = acc[0];
      for (int e = 1; e < 8; ++e) if (acc[e] > l1) { l1 = acc[e]; e1 = e; }
      int e2 = -1; float l2 = -1e30f;
      for (int e = 0; e < 8; ++e) { if (e == e1) continue; if (acc[e] > l2) { l2 = acc[e]; e2 = e; } }
      float tt = expf(l2 - l1);          // <= 1
      float g1 = 1.f / (1.f + tt);
      float g2 = tt / (1.f + tt);
      topidx[t * 2] = e1; topidx[t * 2 + 1] = e2;
      gates[t * 2] = g1;  gates[t * 2 + 1] = g2;
    }
  } else if (b < PREP_W1_BLOCKS + PREP_GATE_BLOCKS + PREP_W2_BLOCKS) {
    // ---- w2sum[e,h] = sum_d W2[e,h,d] ----
    int bx = b - (PREP_W1_BLOCKS + PREP_GATE_BLOCKS);
    int wid = tid >> 6, lane = tid & 63;
    int row = bx * 4 + wid;  // E*H rows
    const float4* r4 = (const float4*)(w2 + (size_t)row * D_DIM);
    // batch all 8 independent loads first
    float4 v[8];
#pragma unroll
    for (int i = 0; i < 8; ++i) v[i] = r4[i * 64 + lane];
    float p = 0.f;
#pragma unroll
    for (int i = 0; i < 8; ++i) p += v[i].x + v[i].y + v[i].z + v[i].w;
#pragma unroll
    for (int off = 1; off < 64; off <<= 1) p += __shfl_xor(p, off);
    if (lane == 0) w2s[row] = p;
  } else if (b < PREP_W1_BLOCKS + PREP_GATE_BLOCKS + PREP_W2_BLOCKS + 2) {
    // ---- b2sum[e] = sum_d b2[e,d] ----
    int local = b - (PREP_W1_BLOCKS + PREP_GATE_BLOCKS + PREP_W2_BLOCKS);
    int w = tid >> 6, lane = tid & 63;
    int e = local * 4 + w;
    float p = 0.f;
    for (int i = lane; i < D_DIM; i += 64) p += b2[e * D_DIM + i];
#pragma unroll
    for (int off = 1; off < 64; off <<= 1) p += __shfl_xor(p, off);
    if (lane == 0) b2sum[e] = p;
  } else {
    // ---- init: s_out = 0, slot_token = T_TOK (zero-row), xbf pad row = 0 ----
    for (int i = tid; i < E_NUM * CAP; i += 256) { s_out[i] = 0.f; slot_token[i] = T_TOK; }
    for (int i = tid; i < D_DIM; i += 256) xbf[(size_t)T_TOK * D_DIM + i] = 0;
  }
}

// ------- GShard dispatch scan (single block, deterministic) -------
__global__ __launch_bounds__(1024) void scan_kernel(
    const int* __restrict__ topidx, int* __restrict__ slot_token,
    int* __restrict__ tok_slot, int* __restrict__ kept_count)
{
  __shared__ int cnts[1024 * 8];
  __shared__ int tot0[8];
  int tid = threadIdx.x;
  int w = tid >> 6, lane = tid & 63;

  int base_t = tid * 8;
  int lc[8]; int myi[8];
  // ---------- j = 0 ----------
#pragma unroll
  for (int e = 0; e < 8; ++e) lc[e] = 0;
#pragma unroll
  for (int u = 0; u < 8; ++u) { int ex = topidx[(base_t + u) * 2]; myi[u] = ex; lc[ex]++; }
#pragma unroll
  for (int e = 0; e < 8; ++e) cnts[tid * 8 + e] = lc[e];
  __syncthreads();
  if (w < 8) {
    int e = w;
    int vals[16]; int lsum = 0;
#pragma unroll
    for (int m = 0; m < 16; ++m) { vals[m] = cnts[(lane * 16 + m) * 8 + e]; lsum += vals[m]; }
    int inc = lsum;
    for (int off = 1; off < 64; off <<= 1) { int o = __shfl_up(inc, off); if (lane >= off) inc += o; }
    int run = inc - lsum;
#pragma unroll
    for (int m = 0; m < 16; ++m) { int v = vals[m]; cnts[(lane * 16 + m) * 8 + e] = run; run += v; }
    if (lane == 63) tot0[e] = run;
  }
  __syncthreads();
  int baseo[8];
#pragma unroll
  for (int e = 0; e < 8; ++e) baseo[e] = cnts[tid * 8 + e];
#pragma unroll
  for (int u = 0; u < 8; ++u) {
    int ex = myi[u]; int t = base_t + u;
    int pos = baseo[ex]++;
    if (pos < CAP) { tok_slot[t * 2] = ex * CAP + pos; slot_token[ex * CAP + pos] = t; }
    else tok_slot[t * 2] = -1;
  }
  __syncthreads();
  // ---------- j = 1 ----------
#pragma unroll
  for (int e = 0; e < 8; ++e) lc[e] = 0;
#pragma unroll
  for (int u = 0; u < 8; ++u) { int ex = topidx[(base_t + u) * 2 + 1]; myi[u] = ex; lc[ex]++; }
#pragma unroll
  for (int e = 0; e < 8; ++e) cnts[tid * 8 + e] = lc[e];
  __syncthreads();
  if (w < 8) {
    int e = w;
    int vals[16]; int lsum = 0;
#pragma unroll
    for (int m = 0; m < 16; ++m) { vals[m] = cnts[(lane * 16 + m) * 8 + e]; lsum += vals[m]; }
    int inc = lsum;
    for (int off = 1; off < 64; off <<= 1) { int o = __shfl_up(inc, off); if (lane >= off) inc += o; }
    int run = tot0[e] + inc - lsum;
#pragma unroll
    for (int m = 0; m < 16; ++m) { int v = vals[m]; cnts[(lane * 16 + m) * 8 + e] = run; run += v; }
    if (lane == 63) kept_count[e] = min(run, CAP);
  }
  __syncthreads();
#pragma unroll
  for (int e = 0; e < 8; ++e) baseo[e] = cnts[tid * 8 + e];
#pragma unroll
  for (int u = 0; u < 8; ++u) {
    int ex = myi[u]; int t = base_t + u;
    int pos = baseo[ex]++;
    if (pos < CAP) { tok_slot[t * 2 + 1] = ex * CAP + pos; slot_token[ex * CAP + pos] = t; }
    else tok_slot[t * 2 + 1] = -1;
  }
}

// ======================================================================
// 256x256-tile, BK=64, 8-wave (2Mx4N), 8-phase bf16 MFMA GEMM with
// counted-vmcnt pipelining, XOR-swizzled LDS (conflict-free ds_read_b128),
// fused relu + w2sum-dot epilogue.  (unchanged from R0 -> R1)
// ======================================================================
#define FFN_NT 32   // K tiles of 64 over D_DIM=2048

__global__ __launch_bounds__(512, 2) void ffn_kernel(
    const unsigned short* __restrict__ xbf,    // [(T+1)][D] bf16
    const unsigned short* __restrict__ w1t,    // [E][H][D] bf16
    const float* __restrict__ w2s,             // [E][H]
    const float* __restrict__ b1,              // [E][H]
    const int* __restrict__ slot_token,        // [E][CAP]
    const int* __restrict__ kept_count,        // [E]
    float* __restrict__ s_out)                 // [E][CAP]
{
  int bid = blockIdx.x;
  int swz = (bid & 7) * 64 + (bid >> 3);   // bijective XCD swizzle (512 % 8 == 0)
  int e = swz >> 6;
  int rem = swz & 63;
  int mt = rem >> 3, nt = rem & 7;
  if (mt * 256 >= kept_count[e]) return;

  __shared__ unsigned short Asl[4][256 * 32];   // 64 KB
  __shared__ unsigned short Bsl[4][256 * 32];   // 64 KB

  int tid = threadIdx.x;
  int w = tid >> 6, lane = tid & 63;
  int wr = w >> 2, wc = w & 3;                  // 2M x 4N waves
  int l15 = lane & 15, q = lane >> 4;

  // ---- staging source setup (pre-swizzled per-lane global addresses) ----
  int r0s = tid >> 2;                           // rows 0..127 (chunk = 16B)
  int ccs = tid & 3;                            // chunk within 64B row
  int sw0 = (ccs ^ ((r0s >> 1) & 3)) * 8;       // swizzled element offset
  int r1s = r0s + 128;
  int sw1 = (ccs ^ ((r1s >> 1) & 3)) * 8;
  int tokl = slot_token[e * CAP + mt * 256 + r0s];
  int tokh = slot_token[e * CAP + mt * 256 + r1s];
  const unsigned short* gA0 = xbf + (size_t)tokl * D_DIM + sw0;
  const unsigned short* gA1 = xbf + (size_t)tokh * D_DIM + sw1;
  const unsigned short* gB0 = w1t + ((size_t)e * H_DIM + nt * 256 + r0s) * D_DIM + sw0;
  const unsigned short* gB1 = w1t + ((size_t)e * H_DIM + nt * 256 + r1s) * D_DIM + sw1;

  // ---- fragment ds_read addressing (same swizzle) ----
  int rowAa = wr * 128 + l15;
  int rowBb = wc * 64 + l15;
  int offA = rowAa * 32 + (q ^ ((rowAa >> 1) & 3)) * 8;
  int offB = rowBb * 32 + (q ^ ((rowBb >> 1) & 3)) * 8;

  // one STAGE = one half-slab = 2 loads/thread (vmcnt counts 2 per slab)
#define STAGE(SLOT_PTR, G0, G1, KOFS)                                    \
  do {                                                                   \
    async_load16((G0) + (KOFS), (SLOT_PTR) + w * 512);                   \
    async_load16((G1) + (KOFS), (SLOT_PTR) + 4096 + w * 512);            \
  } while (0)

  f32x4 acc[8][4];
#pragma unroll
  for (int i = 0; i < 8; ++i)
#pragma unroll
    for (int j = 0; j < 4; ++j) acc[i][j] = (f32x4)(0.f);

  // ---- prologue: stage (0,A0)(0,B0)(0,A1)(0,B1)(1,A0)(1,B0) ----
  STAGE(&Asl[0][0], gA0, gA1, 0);
  STAGE(&Bsl[0][0], gB0, gB1, 0);
  STAGE(&Asl[1][0], gA0, gA1, 32);
  STAGE(&Bsl[1][0], gB0, gB1, 32);
  STAGE(&Asl[2][0], gA0, gA1, 64);
  STAGE(&Bsl[2][0], gB0, gB1, 64);
  asm volatile("s_waitcnt vmcnt(4)" ::: "memory");   // tile 0 landed, 2 slabs in flight
  __builtin_amdgcn_s_barrier();
  __builtin_amdgcn_sched_barrier(0);

  for (int t = 0; t < FFN_NT; ++t) {
    int d = t & 1;
    const unsigned short* Ak0 = &Asl[d * 2][0];
    const unsigned short* Ak1 = &Asl[d * 2 + 1][0];
    const unsigned short* Bk0 = &Bsl[d * 2][0];
    const unsigned short* Bk1 = &Bsl[d * 2 + 1][0];

    bf16x8 aF[4], bK0[4], bK1[4];

    // ===== phase 0: read A(kh0,m0-3)+B(kh0); stage (t+1,A1); mfma m0-3 kh0 =====
#pragma unroll
    for (int mf = 0; mf < 4; ++mf) aF[mf] = *(const bf16x8*)(Ak0 + offA + mf * 512);
#pragma unroll
    for (int nf = 0; nf < 4; ++nf) bK0[nf] = *(const bf16x8*)(Bk0 + offB + nf * 512);
    if (t < FFN_NT - 1) STAGE(&Asl[(d ^ 1) * 2 + 1][0], gA0, gA1, (t + 1) * 64 + 32);
    __builtin_amdgcn_s_barrier();
    __builtin_amdgcn_sched_barrier(0);
    __builtin_amdgcn_s_setprio(1);
#pragma unroll
    for (int mf = 0; mf < 4; ++mf)
#pragma unroll
      for (int nf = 0; nf < 4; ++nf)
        acc[mf][nf] = __builtin_amdgcn_mfma_f32_16x16x32_bf16(aF[mf], bK0[nf], acc[mf][nf], 0, 0, 0);
    __builtin_amdgcn_s_setprio(0);
    __builtin_amdgcn_s_barrier();
    __builtin_amdgcn_sched_barrier(0);

    // ===== phase 1: read A(kh0,m4-7)+B(kh1); stage (t+1,B1); mfma m4-7 kh0 =====
#pragma unroll
    for (int mf = 0; mf < 4; ++mf) aF[mf] = *(const bf16x8*)(Ak0 + offA + (mf + 4) * 512);
#pragma unroll
    for (int nf = 0; nf < 4; ++nf) bK1[nf] = *(const bf16x8*)(Bk1 + offB + nf * 512);
    if (t < FFN_NT - 1) STAGE(&Bsl[(d ^ 1) * 2 + 1][0], gB0, gB1, (t + 1) * 64 + 32);
    __builtin_amdgcn_s_barrier();
    __builtin_amdgcn_sched_barrier(0);
    __builtin_amdgcn_s_setprio(1);
#pragma unroll
    for (int mf = 0; mf < 4; ++mf)
#pragma unroll
      for (int nf = 0; nf < 4; ++nf)
        acc[mf + 4][nf] = __builtin_amdgcn_mfma_f32_16x16x32_bf16(aF[mf], bK0[nf], acc[mf + 4][nf], 0, 0, 0);
    __builtin_amdgcn_s_setprio(0);
    __builtin_amdgcn_s_barrier();
    __builtin_amdgcn_sched_barrier(0);

    // ===== phase 2: read A(kh1,m0-3); stage (t+2,A0); mfma m0-3 kh1 =====
#pragma unroll
    for (int mf = 0; mf < 4; ++mf) aF[mf] = *(const bf16x8*)(Ak1 + offA + mf * 512);
    if (t < FFN_NT - 2) STAGE(&Asl[d * 2][0], gA0, gA1, (t + 2) * 64);
    __builtin_amdgcn_s_barrier();
    __builtin_amdgcn_sched_barrier(0);
    __builtin_amdgcn_s_setprio(1);
#pragma unroll
    for (int mf = 0; mf < 4; ++mf)
#pragma unroll
      for (int nf = 0; nf < 4; ++nf)
        acc[mf][nf] = __builtin_amdgcn_mfma_f32_16x16x32_bf16(aF[mf], bK1[nf], acc[mf][nf], 0, 0, 0);
    __builtin_amdgcn_s_setprio(0);
    __builtin_amdgcn_s_barrier();
    __builtin_amdgcn_sched_barrier(0);

    // ===== phase 3: read A(kh1,m4-7); stage (t+2,B0); mfma m4-7 kh1; boundary =====
#pragma unroll
    for (int mf = 0; mf < 4; ++mf) aF[mf] = *(const bf16x8*)(Ak1 + offA + (mf + 4) * 512);
    if (t < FFN_NT - 2) STAGE(&Bsl[d * 2][0], gB0, gB1, (t + 2) * 64);
    __builtin_amdgcn_s_barrier();
    __builtin_amdgcn_sched_barrier(0);
    __builtin_amdgcn_s_setprio(1);
#pragma unroll
    for (int mf = 0; mf < 4; ++mf)
#pragma unroll
      for (int nf = 0; nf < 4; ++nf)
        acc[mf + 4][nf] = __builtin_amdgcn_mfma_f32_16x16x32_bf16(aF[mf], bK1[nf], acc[mf + 4][nf], 0, 0, 0);
    __builtin_amdgcn_s_setprio(0);
    if (t < FFN_NT - 2) {
      // tile t+1 fully landed; 2 slabs (t+2,A0)(t+2,B0) stay in flight
      asm volatile("s_waitcnt vmcnt(4)" ::: "memory");
    } else {
      // no further prefetch: drain before the last tile
      asm volatile("s_waitcnt vmcnt(0)" ::: "memory");
    }
    __builtin_amdgcn_s_barrier();
    __builtin_amdgcn_sched_barrier(0);
  }
#undef STAGE

  // ---- epilogue: s[m] = sum_n relu(z + b1[n]) * w2sum[n] ----
  float sp[8][4];
#pragma unroll
  for (int mf = 0; mf < 8; ++mf)
#pragma unroll
    for (int r = 0; r < 4; ++r) sp[mf][r] = 0.f;
#pragma unroll
  for (int nf = 0; nf < 4; ++nf) {
    int n = nt * 256 + wc * 64 + nf * 16 + l15;
    float w2v = w2s[e * H_DIM + n];
    float b1v = b1[e * H_DIM + n];
#pragma unroll
    for (int mf = 0; mf < 8; ++mf)
#pragma unroll
      for (int r = 0; r < 4; ++r) {
        float z = acc[mf][nf][r] + b1v;
        sp[mf][r] += fmaxf(z, 0.f) * w2v;
      }
  }
#pragma unroll
  for (int off = 1; off < 16; off <<= 1)
#pragma unroll
    for (int mf = 0; mf < 8; ++mf)
#pragma unroll
      for (int r = 0; r < 4; ++r) sp[mf][r] += __shfl_xor(sp[mf][r], off);
  if (l15 == 0) {
    int mbase = e * CAP + mt * 256 + wr * 128 + q * 4;
#pragma unroll
    for (int mf = 0; mf < 8; ++mf)
#pragma unroll
      for (int r = 0; r < 4; ++r)
        atomicAdd(&s_out[mbase + mf * 16 + r], sp[mf][r]);
  }
}

// ---------------- combine + per-batch log_softmax ----------------
__global__ __launch_bounds__(1024) void combine_kernel(
    const float* __restrict__ s_in, const int* __restrict__ tok_slot,
    const float* __restrict__ gates, const float* __restrict__ b2sum,
    float* __restrict__ out)
{
  __shared__ float red[1024];
  int b = blockIdx.x, tid = threadIdx.x;
  float y[2];
  float mx = -1e30f;
#pragma unroll
  for (int i = 0; i < 2; ++i) {
    int t = b * 2048 + i * 1024 + tid;
    float accv = 0.f;
#pragma unroll
    for (int j = 0; j < 2; ++j) {
      int sl = tok_slot[t * 2 + j];
      if (sl >= 0) accv += gates[t * 2 + j] * (s_in[sl] + b2sum[sl >> 11]);
    }
    y[i] = accv;
    mx = fmaxf(mx, accv);
  }
  red[tid] = mx; __syncthreads();
  for (int st = 512; st > 0; st >>= 1) {
    if (tid < st) red[tid] = fmaxf(red[tid], red[tid + st]);
    __syncthreads();
  }
  mx = red[0]; __syncthreads();
  float se = 0.f;
#pragma unroll
  for (int i = 0; i < 2; ++i) se += expf(y[i] - mx);
  red[tid] = se; __syncthreads();
  for (int st = 512; st > 0; st >>= 1) {
    if (tid < st) red[tid] += red[tid + st];
    __syncthreads();
  }
  float logZ = mx + logf(red[0]);
#pragma unroll
  for (int i = 0; i < 2; ++i) out[b * 2048 + i * 1024 + tid] = y[i] - logZ;
}

extern "C" void kernel_launch(void* const* d_in, const int* in_sizes, int n_in,
                              void* d_out, int out_size, void* d_ws, size_t ws_size,
                              hipStream_t stream) {
  const float* x  = (const float*)d_in[0];
  const float* wg = (const float*)d_in[1];
  const float* w1 = (const float*)d_in[2];
  const float* b1 = (const float*)d_in[3];
  const float* w2 = (const float*)d_in[4];
  const float* b2 = (const float*)d_in[5];
  float* out = (float*)d_out;

  char* ws = (char*)d_ws;
  size_t off = 0;
  auto alloc = [&](size_t bytes) -> void* {
    void* p = ws + off; off += (bytes + 255) & ~(size_t)255; return p;
  };
  unsigned short* xbf   = (unsigned short*)alloc((size_t)(T_TOK + 1) * D_DIM * 2);
  unsigned short* w1t   = (unsigned short*)alloc((size_t)E_NUM * D_DIM * H_DIM * 2);
  float* w2s            = (float*)alloc((size_t)E_NUM * H_DIM * 4);
  float* gates          = (float*)alloc((size_t)T_TOK * 2 * 4);
  int*   topidx         = (int*)alloc((size_t)T_TOK * 2 * 4);
  int*   tok_slot       = (int*)alloc((size_t)T_TOK * 2 * 4);
  int*   slot_token     = (int*)alloc((size_t)E_NUM * CAP * 4);
  float* s_buf          = (float*)alloc((size_t)E_NUM * CAP * 4);
  float* b2s            = (float*)alloc(256);
  int*   kept           = (int*)alloc(256);

  prep_kernel<<<PREP_TOTAL, 256, 0, stream>>>(x, wg, w1, w2, b2, xbf, topidx,
                                              gates, w1t, w2s, b2s, slot_token, s_buf);
  scan_kernel<<<1, 1024, 0, stream>>>(topidx, slot_token, tok_slot, kept);
  ffn_kernel<<<E_NUM * 8 * 8, 512, 0, stream>>>(xbf, w1t, w2s, b1, slot_token, kept, s_buf);
  combine_kernel<<<4, 1024, 0, stream>>>(s_buf, tok_slot, gates, b2s, out);
}

// Round 3
// 550.632 us; speedup vs baseline: 1.0155x; 1.0155x over previous
//
#include <hip/hip_runtime.h>
#include <hip/hip_bf16.h>
#include <math.h>

#define T_TOK 8192
#define D_DIM 2048
#define H_DIM 2048
#define E_NUM 8
#define CAP   2048

typedef __attribute__((ext_vector_type(4))) float f32x4;
typedef __attribute__((ext_vector_type(8))) __bf16 bf16x8;

__device__ __forceinline__ unsigned short f2bf(float f) {
  unsigned int u = __float_as_uint(f);
  return (unsigned short)((u + 0x7FFFu + ((u >> 16) & 1u)) >> 16);
}

__device__ __forceinline__ void async_load16(const void* g, void* l) {
  __builtin_amdgcn_global_load_lds(
      (const __attribute__((address_space(1))) void*)g,
      (__attribute__((address_space(3))) void*)l, 16, 0, 0);
}

// ---- fused prep, R2: role-INTERLEAVED grid (groups of 5 = 2xW1 + 1xgate +
// 2xW2) so resident cohorts mix read/write/compute phases (anti-lockstep),
// and W1 blocks process 2 adjacent tiles with dual LDS buffers + single
// barrier (deeper memory pipeline: 32 KB in flight per block). ----
#define PREP_GROUPS 2048
#define PREP_TOTAL (PREP_GROUPS * 5 + 3)   // 10243

__global__ __launch_bounds__(256) void prep_kernel(
    const float* __restrict__ x, const float* __restrict__ wg,
    const float* __restrict__ w1, const float* __restrict__ w2,
    const float* __restrict__ b2,
    unsigned short* __restrict__ xbf, int* __restrict__ topidx,
    float* __restrict__ gates, unsigned short* __restrict__ w1t,
    float* __restrict__ w2s, float* __restrict__ b2sum,
    int* __restrict__ slot_token, float* __restrict__ s_out)
{
  __shared__ unsigned short tile[2][64][68];
  int b = blockIdx.x;
  int tid = threadIdx.x;

  int g = b / 5, r = b - g * 5;
  bool tail = (b >= PREP_GROUPS * 5);

  if (!tail && r < 2) {
    // ---- W1 [E][D][H] fp32 -> W1T [E][H][D] bf16; 2 tiles per block ----
    int wb = g * 2 + r;                 // 0..4095
    int tixA = wb * 2, tixB = wb * 2 + 1;   // tiles 0..8191
    int eA = tixA >> 10, remA = tixA & 1023, dtA = remA >> 5, htA = remA & 31;
    int eB = tixB >> 10, remB = tixB & 1023, dtB = remB >> 5, htB = remB & 31;
    const float* ibaseA = w1 + ((size_t)eA * D_DIM + dtA * 64) * H_DIM + htA * 64;
    const float* ibaseB = w1 + ((size_t)eB * D_DIM + dtB * 64) * H_DIM + htB * 64;
    int c4 = tid & 15, r0 = tid >> 4;
    // issue all 8 independent 16B loads up front (32 KB/block in flight)
    float4 va[4], vb[4];
#pragma unroll
    for (int p = 0; p < 4; ++p)
      va[p] = *(const float4*)(ibaseA + (size_t)(r0 + p * 16) * H_DIM + c4 * 4);
#pragma unroll
    for (int p = 0; p < 4; ++p)
      vb[p] = *(const float4*)(ibaseB + (size_t)(r0 + p * 16) * H_DIM + c4 * 4);
#pragma unroll
    for (int p = 0; p < 4; ++p) {
      int rr = r0 + p * 16;
      tile[0][rr][c4 * 4 + 0] = f2bf(va[p].x);
      tile[0][rr][c4 * 4 + 1] = f2bf(va[p].y);
      tile[0][rr][c4 * 4 + 2] = f2bf(va[p].z);
      tile[0][rr][c4 * 4 + 3] = f2bf(va[p].w);
      tile[1][rr][c4 * 4 + 0] = f2bf(vb[p].x);
      tile[1][rr][c4 * 4 + 1] = f2bf(vb[p].y);
      tile[1][rr][c4 * 4 + 2] = f2bf(vb[p].z);
      tile[1][rr][c4 * 4 + 3] = f2bf(vb[p].w);
    }
    __syncthreads();
    int dq = tid & 7, h0 = tid >> 3;
    unsigned short* obaseA = w1t + ((size_t)eA * H_DIM + htA * 64) * D_DIM + dtA * 64;
    unsigned short* obaseB = w1t + ((size_t)eB * H_DIM + htB * 64) * D_DIM + dtB * 64;
#pragma unroll
    for (int tb = 0; tb < 2; ++tb) {
      unsigned short* obase = tb ? obaseB : obaseA;
      unsigned int lo[2][4], hi[2][4];
#pragma unroll
      for (int p = 0; p < 2; ++p) {
        int hh = h0 + p * 32;
#pragma unroll
        for (int u = 0; u < 4; ++u) {
          lo[p][u] = tile[tb][dq * 8 + u * 2][hh];
          hi[p][u] = tile[tb][dq * 8 + u * 2 + 1][hh];
        }
      }
#pragma unroll
      for (int p = 0; p < 2; ++p) {
        int hh = h0 + p * 32;
        uint4 ov = make_uint4(lo[p][0] | (hi[p][0] << 16), lo[p][1] | (hi[p][1] << 16),
                              lo[p][2] | (hi[p][2] << 16), lo[p][3] | (hi[p][3] << 16));
        *(uint4*)(obase + (size_t)hh * D_DIM + dq * 8) = ov;
      }
    }
  } else if (!tail && r == 2) {
    // ---- gating (fp32 logits, top-2, softmax gates) + x -> bf16 cast ----
    int bx = g;                          // 0..2047
    int w = tid >> 6, lane = tid & 63;
    int t = bx * 4 + w;
    const float4* xr = (const float4*)(x + (size_t)t * D_DIM);
    ushort4* xo = (ushort4*)(xbf + (size_t)t * D_DIM);
    float4 v[8];
#pragma unroll
    for (int it = 0; it < 8; ++it) v[it] = xr[it * 64 + lane];
    float acc[8];
#pragma unroll
    for (int e = 0; e < 8; ++e) acc[e] = 0.f;
#pragma unroll
    for (int it = 0; it < 8; ++it) {
      int i4 = it * 64 + lane;
      int d = i4 * 4;
      float xv[4] = {v[it].x, v[it].y, v[it].z, v[it].w};
#pragma unroll
      for (int u = 0; u < 4; ++u) {
        const float4* wr = (const float4*)(wg + (size_t)(d + u) * 8);
        float4 w01 = wr[0], w23 = wr[1];
        acc[0] += xv[u] * w01.x; acc[1] += xv[u] * w01.y;
        acc[2] += xv[u] * w01.z; acc[3] += xv[u] * w01.w;
        acc[4] += xv[u] * w23.x; acc[5] += xv[u] * w23.y;
        acc[6] += xv[u] * w23.z; acc[7] += xv[u] * w23.w;
      }
      ushort4 o;
      o.x = f2bf(v[it].x); o.y = f2bf(v[it].y); o.z = f2bf(v[it].z); o.w = f2bf(v[it].w);
      xo[i4] = o;
    }
#pragma unroll
    for (int off = 1; off < 64; off <<= 1) {
#pragma unroll
      for (int e = 0; e < 8; ++e) acc[e] += __shfl_xor(acc[e], off);
    }
    if (lane == 0) {
      int e1 = 0; float l1 = acc[0];
      for (int e = 1; e < 8; ++e) if (acc[e] > l1) { l1 = acc[e]; e1 = e; }
      int e2 = -1; float l2 = -1e30f;
      for (int e = 0; e < 8; ++e) { if (e == e1) continue; if (acc[e] > l2) { l2 = acc[e]; e2 = e; } }
      float tt = expf(l2 - l1);          // <= 1
      float g1 = 1.f / (1.f + tt);
      float g2 = tt / (1.f + tt);
      topidx[t * 2] = e1; topidx[t * 2 + 1] = e2;
      gates[t * 2] = g1;  gates[t * 2 + 1] = g2;
    }
  } else if (!tail) {
    // ---- w2sum[e,h] = sum_d W2[e,h,d] ----
    int bx = g * 2 + (r - 3);            // 0..4095
    int wid = tid >> 6, lane = tid & 63;
    int row = bx * 4 + wid;              // E*H rows
    const float4* r4 = (const float4*)(w2 + (size_t)row * D_DIM);
    float4 v[8];
#pragma unroll
    for (int i = 0; i < 8; ++i) v[i] = r4[i * 64 + lane];
    float p = 0.f;
#pragma unroll
    for (int i = 0; i < 8; ++i) p += v[i].x + v[i].y + v[i].z + v[i].w;
#pragma unroll
    for (int off = 1; off < 64; off <<= 1) p += __shfl_xor(p, off);
    if (lane == 0) w2s[row] = p;
  } else {
    int local = b - PREP_GROUPS * 5;     // 0,1: b2sum ; 2: init
    if (local < 2) {
      int w = tid >> 6, lane = tid & 63;
      int e = local * 4 + w;
      float p = 0.f;
      for (int i = lane; i < D_DIM; i += 64) p += b2[e * D_DIM + i];
#pragma unroll
      for (int off = 1; off < 64; off <<= 1) p += __shfl_xor(p, off);
      if (lane == 0) b2sum[e] = p;
    } else {
      for (int i = tid; i < E_NUM * CAP; i += 256) { s_out[i] = 0.f; slot_token[i] = T_TOK; }
      for (int i = tid; i < D_DIM; i += 256) xbf[(size_t)T_TOK * D_DIM + i] = 0;
    }
  }
}

// ------- GShard dispatch scan (single block, deterministic) -------
__global__ __launch_bounds__(1024) void scan_kernel(
    const int* __restrict__ topidx, int* __restrict__ slot_token,
    int* __restrict__ tok_slot, int* __restrict__ kept_count)
{
  __shared__ int cnts[1024 * 8];
  __shared__ int tot0[8];
  int tid = threadIdx.x;
  int w = tid >> 6, lane = tid & 63;

  int base_t = tid * 8;
  int lc[8]; int myi[8];
  // ---------- j = 0 ----------
#pragma unroll
  for (int e = 0; e < 8; ++e) lc[e] = 0;
#pragma unroll
  for (int u = 0; u < 8; ++u) { int ex = topidx[(base_t + u) * 2]; myi[u] = ex; lc[ex]++; }
#pragma unroll
  for (int e = 0; e < 8; ++e) cnts[tid * 8 + e] = lc[e];
  __syncthreads();
  if (w < 8) {
    int e = w;
    int vals[16]; int lsum = 0;
#pragma unroll
    for (int m = 0; m < 16; ++m) { vals[m] = cnts[(lane * 16 + m) * 8 + e]; lsum += vals[m]; }
    int inc = lsum;
    for (int off = 1; off < 64; off <<= 1) { int o = __shfl_up(inc, off); if (lane >= off) inc += o; }
    int run = inc - lsum;
#pragma unroll
    for (int m = 0; m < 16; ++m) { int v = vals[m]; cnts[(lane * 16 + m) * 8 + e] = run; run += v; }
    if (lane == 63) tot0[e] = run;
  }
  __syncthreads();
  int baseo[8];
#pragma unroll
  for (int e = 0; e < 8; ++e) baseo[e] = cnts[tid * 8 + e];
#pragma unroll
  for (int u = 0; u < 8; ++u) {
    int ex = myi[u]; int t = base_t + u;
    int pos = baseo[ex]++;
    if (pos < CAP) { tok_slot[t * 2] = ex * CAP + pos; slot_token[ex * CAP + pos] = t; }
    else tok_slot[t * 2] = -1;
  }
  __syncthreads();
  // ---------- j = 1 ----------
#pragma unroll
  for (int e = 0; e < 8; ++e) lc[e] = 0;
#pragma unroll
  for (int u = 0; u < 8; ++u) { int ex = topidx[(base_t + u) * 2 + 1]; myi[u] = ex; lc[ex]++; }
#pragma unroll
  for (int e = 0; e < 8; ++e) cnts[tid * 8 + e] = lc[e];
  __syncthreads();
  if (w < 8) {
    int e = w;
    int vals[16]; int lsum = 0;
#pragma unroll
    for (int m = 0; m < 16; ++m) { vals[m] = cnts[(lane * 16 + m) * 8 + e]; lsum += vals[m]; }
    int inc = lsum;
    for (int off = 1; off < 64; off <<= 1) { int o = __shfl_up(inc, off); if (lane >= off) inc += o; }
    int run = tot0[e] + inc - lsum;
#pragma unroll
    for (int m = 0; m < 16; ++m) { int v = vals[m]; cnts[(lane * 16 + m) * 8 + e] = run; run += v; }
    if (lane == 63) kept_count[e] = min(run, CAP);
  }
  __syncthreads();
#pragma unroll
  for (int e = 0; e < 8; ++e) baseo[e] = cnts[tid * 8 + e];
#pragma unroll
  for (int u = 0; u < 8; ++u) {
    int ex = myi[u]; int t = base_t + u;
    int pos = baseo[ex]++;
    if (pos < CAP) { tok_slot[t * 2 + 1] = ex * CAP + pos; slot_token[ex * CAP + pos] = t; }
    else tok_slot[t * 2 + 1] = -1;
  }
}

// ======================================================================
// 256x256-tile, BK=64, 8-wave (2Mx4N), 8-phase bf16 MFMA GEMM with
// counted-vmcnt pipelining, XOR-swizzled LDS (conflict-free ds_read_b128),
// fused relu + w2sum-dot epilogue.  (unchanged from R1 -> R2)
// ======================================================================
#define FFN_NT 32   // K tiles of 64 over D_DIM=2048

__global__ __launch_bounds__(512, 2) void ffn_kernel(
    const unsigned short* __restrict__ xbf,    // [(T+1)][D] bf16
    const unsigned short* __restrict__ w1t,    // [E][H][D] bf16
    const float* __restrict__ w2s,             // [E][H]
    const float* __restrict__ b1,              // [E][H]
    const int* __restrict__ slot_token,        // [E][CAP]
    const int* __restrict__ kept_count,        // [E]
    float* __restrict__ s_out)                 // [E][CAP]
{
  int bid = blockIdx.x;
  int swz = (bid & 7) * 64 + (bid >> 3);   // bijective XCD swizzle (512 % 8 == 0)
  int e = swz >> 6;
  int rem = swz & 63;
  int mt = rem >> 3, nt = rem & 7;
  if (mt * 256 >= kept_count[e]) return;

  __shared__ unsigned short Asl[4][256 * 32];   // 64 KB
  __shared__ unsigned short Bsl[4][256 * 32];   // 64 KB

  int tid = threadIdx.x;
  int w = tid >> 6, lane = tid & 63;
  int wr = w >> 2, wc = w & 3;                  // 2M x 4N waves
  int l15 = lane & 15, q = lane >> 4;

  // ---- staging source setup (pre-swizzled per-lane global addresses) ----
  int r0s = tid >> 2;                           // rows 0..127 (chunk = 16B)
  int ccs = tid & 3;                            // chunk within 64B row
  int sw0 = (ccs ^ ((r0s >> 1) & 3)) * 8;       // swizzled element offset
  int r1s = r0s + 128;
  int sw1 = (ccs ^ ((r1s >> 1) & 3)) * 8;
  int tokl = slot_token[e * CAP + mt * 256 + r0s];
  int tokh = slot_token[e * CAP + mt * 256 + r1s];
  const unsigned short* gA0 = xbf + (size_t)tokl * D_DIM + sw0;
  const unsigned short* gA1 = xbf + (size_t)tokh * D_DIM + sw1;
  const unsigned short* gB0 = w1t + ((size_t)e * H_DIM + nt * 256 + r0s) * D_DIM + sw0;
  const unsigned short* gB1 = w1t + ((size_t)e * H_DIM + nt * 256 + r1s) * D_DIM + sw1;

  // ---- fragment ds_read addressing (same swizzle) ----
  int rowAa = wr * 128 + l15;
  int rowBb = wc * 64 + l15;
  int offA = rowAa * 32 + (q ^ ((rowAa >> 1) & 3)) * 8;
  int offB = rowBb * 32 + (q ^ ((rowBb >> 1) & 3)) * 8;

  // one STAGE = one half-slab = 2 loads/thread (vmcnt counts 2 per slab)
#define STAGE(SLOT_PTR, G0, G1, KOFS)                                    \
  do {                                                                   \
    async_load16((G0) + (KOFS), (SLOT_PTR) + w * 512);                   \
    async_load16((G1) + (KOFS), (SLOT_PTR) + 4096 + w * 512);            \
  } while (0)

  f32x4 acc[8][4];
#pragma unroll
  for (int i = 0; i < 8; ++i)
#pragma unroll
    for (int j = 0; j < 4; ++j) acc[i][j] = (f32x4)(0.f);

  // ---- prologue: stage (0,A0)(0,B0)(0,A1)(0,B1)(1,A0)(1,B0) ----
  STAGE(&Asl[0][0], gA0, gA1, 0);
  STAGE(&Bsl[0][0], gB0, gB1, 0);
  STAGE(&Asl[1][0], gA0, gA1, 32);
  STAGE(&Bsl[1][0], gB0, gB1, 32);
  STAGE(&Asl[2][0], gA0, gA1, 64);
  STAGE(&Bsl[2][0], gB0, gB1, 64);
  asm volatile("s_waitcnt vmcnt(4)" ::: "memory");   // tile 0 landed, 2 slabs in flight
  __builtin_amdgcn_s_barrier();
  __builtin_amdgcn_sched_barrier(0);

  for (int t = 0; t < FFN_NT; ++t) {
    int d = t & 1;
    const unsigned short* Ak0 = &Asl[d * 2][0];
    const unsigned short* Ak1 = &Asl[d * 2 + 1][0];
    const unsigned short* Bk0 = &Bsl[d * 2][0];
    const unsigned short* Bk1 = &Bsl[d * 2 + 1][0];

    bf16x8 aF[4], bK0[4], bK1[4];

    // ===== phase 0: read A(kh0,m0-3)+B(kh0); stage (t+1,A1); mfma m0-3 kh0 =====
#pragma unroll
    for (int mf = 0; mf < 4; ++mf) aF[mf] = *(const bf16x8*)(Ak0 + offA + mf * 512);
#pragma unroll
    for (int nf = 0; nf < 4; ++nf) bK0[nf] = *(const bf16x8*)(Bk0 + offB + nf * 512);
    if (t < FFN_NT - 1) STAGE(&Asl[(d ^ 1) * 2 + 1][0], gA0, gA1, (t + 1) * 64 + 32);
    __builtin_amdgcn_s_barrier();
    __builtin_amdgcn_sched_barrier(0);
    __builtin_amdgcn_s_setprio(1);
#pragma unroll
    for (int mf = 0; mf < 4; ++mf)
#pragma unroll
      for (int nf = 0; nf < 4; ++nf)
        acc[mf][nf] = __builtin_amdgcn_mfma_f32_16x16x32_bf16(aF[mf], bK0[nf], acc[mf][nf], 0, 0, 0);
    __builtin_amdgcn_s_setprio(0);
    __builtin_amdgcn_s_barrier();
    __builtin_amdgcn_sched_barrier(0);

    // ===== phase 1: read A(kh0,m4-7)+B(kh1); stage (t+1,B1); mfma m4-7 kh0 =====
#pragma unroll
    for (int mf = 0; mf < 4; ++mf) aF[mf] = *(const bf16x8*)(Ak0 + offA + (mf + 4) * 512);
#pragma unroll
    for (int nf = 0; nf < 4; ++nf) bK1[nf] = *(const bf16x8*)(Bk1 + offB + nf * 512);
    if (t < FFN_NT - 1) STAGE(&Bsl[(d ^ 1) * 2 + 1][0], gB0, gB1, (t + 1) * 64 + 32);
    __builtin_amdgcn_s_barrier();
    __builtin_amdgcn_sched_barrier(0);
    __builtin_amdgcn_s_setprio(1);
#pragma unroll
    for (int mf = 0; mf < 4; ++mf)
#pragma unroll
      for (int nf = 0; nf < 4; ++nf)
        acc[mf + 4][nf] = __builtin_amdgcn_mfma_f32_16x16x32_bf16(aF[mf], bK0[nf], acc[mf + 4][nf], 0, 0, 0);
    __builtin_amdgcn_s_setprio(0);
    __builtin_amdgcn_s_barrier();
    __builtin_amdgcn_sched_barrier(0);

    // ===== phase 2: read A(kh1,m0-3); stage (t+2,A0); mfma m0-3 kh1 =====
#pragma unroll
    for (int mf = 0; mf < 4; ++mf) aF[mf] = *(const bf16x8*)(Ak1 + offA + mf * 512);
    if (t < FFN_NT - 2) STAGE(&Asl[d * 2][0], gA0, gA1, (t + 2) * 64);
    __builtin_amdgcn_s_barrier();
    __builtin_amdgcn_sched_barrier(0);
    __builtin_amdgcn_s_setprio(1);
#pragma unroll
    for (int mf = 0; mf < 4; ++mf)
#pragma unroll
      for (int nf = 0; nf < 4; ++nf)
        acc[mf][nf] = __builtin_amdgcn_mfma_f32_16x16x32_bf16(aF[mf], bK1[nf], acc[mf][nf], 0, 0, 0);
    __builtin_amdgcn_s_setprio(0);
    __builtin_amdgcn_s_barrier();
    __builtin_amdgcn_sched_barrier(0);

    // ===== phase 3: read A(kh1,m4-7); stage (t+2,B0); mfma m4-7 kh1; boundary =====
#pragma unroll
    for (int mf = 0; mf < 4; ++mf) aF[mf] = *(const bf16x8*)(Ak1 + offA + (mf + 4) * 512);
    if (t < FFN_NT - 2) STAGE(&Bsl[d * 2][0], gB0, gB1, (t + 2) * 64);
    __builtin_amdgcn_s_barrier();
    __builtin_amdgcn_sched_barrier(0);
    __builtin_amdgcn_s_setprio(1);
#pragma unroll
    for (int mf = 0; mf < 4; ++mf)
#pragma unroll
      for (int nf = 0; nf < 4; ++nf)
        acc[mf + 4][nf] = __builtin_amdgcn_mfma_f32_16x16x32_bf16(aF[mf], bK1[nf], acc[mf + 4][nf], 0, 0, 0);
    __builtin_amdgcn_s_setprio(0);
    if (t < FFN_NT - 2) {
      // tile t+1 fully landed; 2 slabs (t+2,A0)(t+2,B0) stay in flight
      asm volatile("s_waitcnt vmcnt(4)" ::: "memory");
    } else {
      // no further prefetch: drain before the last tile
      asm volatile("s_waitcnt vmcnt(0)" ::: "memory");
    }
    __builtin_amdgcn_s_barrier();
    __builtin_amdgcn_sched_barrier(0);
  }
#undef STAGE

  // ---- epilogue: s[m] = sum_n relu(z + b1[n]) * w2sum[n] ----
  float sp[8][4];
#pragma unroll
  for (int mf = 0; mf < 8; ++mf)
#pragma unroll
    for (int r = 0; r < 4; ++r) sp[mf][r] = 0.f;
#pragma unroll
  for (int nf = 0; nf < 4; ++nf) {
    int n = nt * 256 + wc * 64 + nf * 16 + l15;
    float w2v = w2s[e * H_DIM + n];
    float b1v = b1[e * H_DIM + n];
#pragma unroll
    for (int mf = 0; mf < 8; ++mf)
#pragma unroll
      for (int r = 0; r < 4; ++r) {
        float z = acc[mf][nf][r] + b1v;
        sp[mf][r] += fmaxf(z, 0.f) * w2v;
      }
  }
#pragma unroll
  for (int off = 1; off < 16; off <<= 1)
#pragma unroll
    for (int mf = 0; mf < 8; ++mf)
#pragma unroll
      for (int r = 0; r < 4; ++r) sp[mf][r] += __shfl_xor(sp[mf][r], off);
  if (l15 == 0) {
    int mbase = e * CAP + mt * 256 + wr * 128 + q * 4;
#pragma unroll
    for (int mf = 0; mf < 8; ++mf)
#pragma unroll
      for (int r = 0; r < 4; ++r)
        atomicAdd(&s_out[mbase + mf * 16 + r], sp[mf][r]);
  }
}

// ---------------- combine + per-batch log_softmax ----------------
__global__ __launch_bounds__(1024) void combine_kernel(
    const float* __restrict__ s_in, const int* __restrict__ tok_slot,
    const float* __restrict__ gates, const float* __restrict__ b2sum,
    float* __restrict__ out)
{
  __shared__ float red[1024];
  int b = blockIdx.x, tid = threadIdx.x;
  float y[2];
  float mx = -1e30f;
#pragma unroll
  for (int i = 0; i < 2; ++i) {
    int t = b * 2048 + i * 1024 + tid;
    float accv = 0.f;
#pragma unroll
    for (int j = 0; j < 2; ++j) {
      int sl = tok_slot[t * 2 + j];
      if (sl >= 0) accv += gates[t * 2 + j] * (s_in[sl] + b2sum[sl >> 11]);
    }
    y[i] = accv;
    mx = fmaxf(mx, accv);
  }
  red[tid] = mx; __syncthreads();
  for (int st = 512; st > 0; st >>= 1) {
    if (tid < st) red[tid] = fmaxf(red[tid], red[tid + st]);
    __syncthreads();
  }
  mx = red[0]; __syncthreads();
  float se = 0.f;
#pragma unroll
  for (int i = 0; i < 2; ++i) se += expf(y[i] - mx);
  red[tid] = se; __syncthreads();
  for (int st = 512; st > 0; st >>= 1) {
    if (tid < st) red[tid] += red[tid + st];
    __syncthreads();
  }
  float logZ = mx + logf(red[0]);
#pragma unroll
  for (int i = 0; i < 2; ++i) out[b * 2048 + i * 1024 + tid] = y[i] - logZ;
}

extern "C" void kernel_launch(void* const* d_in, const int* in_sizes, int n_in,
                              void* d_out, int out_size, void* d_ws, size_t ws_size,
                              hipStream_t stream) {
  const float* x  = (const float*)d_in[0];
  const float* wg = (const float*)d_in[1];
  const float* w1 = (const float*)d_in[2];
  const float* b1 = (const float*)d_in[3];
  const float* w2 = (const float*)d_in[4];
  const float* b2 = (const float*)d_in[5];
  float* out = (float*)d_out;

  char* ws = (char*)d_ws;
  size_t off = 0;
  auto alloc = [&](size_t bytes) -> void* {
    void* p = ws + off; off += (bytes + 255) & ~(size_t)255; return p;
  };
  unsigned short* xbf   = (unsigned short*)alloc((size_t)(T_TOK + 1) * D_DIM * 2);
  unsigned short* w1t   = (unsigned short*)alloc((size_t)E_NUM * D_DIM * H_DIM * 2);
  float* w2s            = (float*)alloc((size_t)E_NUM * H_DIM * 4);
  float* gates          = (float*)alloc((size_t)T_TOK * 2 * 4);
  int*   topidx         = (int*)alloc((size_t)T_TOK * 2 * 4);
  int*   tok_slot       = (int*)alloc((size_t)T_TOK * 2 * 4);
  int*   slot_token     = (int*)alloc((size_t)E_NUM * CAP * 4);
  float* s_buf          = (float*)alloc((size_t)E_NUM * CAP * 4);
  float* b2s            = (float*)alloc(256);
  int*   kept           = (int*)alloc(256);

  prep_kernel<<<PREP_TOTAL, 256, 0, stream>>>(x, wg, w1, w2, b2, xbf, topidx,
                                              gates, w1t, w2s, b2s, slot_token, s_buf);
  scan_kernel<<<1, 1024, 0, stream>>>(topidx, slot_token, tok_slot, kept);
  ffn_kernel<<<E_NUM * 8 * 8, 512, 0, stream>>>(xbf, w1t, w2s, b1, slot_token, kept, s_buf);
  combine_kernel<<<4, 1024, 0, stream>>>(s_buf, tok_slot, gates, b2s, out);
}

// Round 4
// 529.972 us; speedup vs baseline: 1.0551x; 1.0390x over previous
//
#include <hip/hip_runtime.h>
#include <hip/hip_bf16.h>
#include <math.h>

#define T_TOK 8192
#define D_DIM 2048
#define H_DIM 2048
#define E_NUM 8
#define CAP   2048
#define CHUNKS 32   // dispatch-count chunks of 256 tokens

typedef __attribute__((ext_vector_type(4))) float f32x4;
typedef __attribute__((ext_vector_type(8))) __bf16 bf16x8;

__device__ __forceinline__ unsigned short f2bf(float f) {
  unsigned int u = __float_as_uint(f);
  return (unsigned short)((u + 0x7FFFu + ((u >> 16) & 1u)) >> 16);
}

__device__ __forceinline__ void async_load16(const void* g, void* l) {
  __builtin_amdgcn_global_load_lds(
      (const __attribute__((address_space(1))) void*)g,
      (__attribute__((address_space(3))) void*)l, 16, 0, 0);
}

// ===================== R3: prep split into 4 kernels =====================
// Rationale: 3 rounds of within-megakernel changes moved prep 170->166us
// while no pipe shows busy. Splitting gives per-phase dur_us in the
// profile (ablation by construction) and unhides ffn/scan in top-5.

// ---- W1 [E][D][H] fp32 -> W1T [E][H][D] bf16; 2 tiles/block; 4096 blocks ----
// block 0 additionally zeroes the dispatch counters (gate runs after us).
__global__ __launch_bounds__(256) void w1cast_kernel(
    const float* __restrict__ w1, unsigned short* __restrict__ w1t,
    int* __restrict__ cnt2)
{
  __shared__ unsigned short tile[2][64][68];
  int b = blockIdx.x;
  int tid = threadIdx.x;
  if (b == 0) {
    for (int i = tid; i < 2 * CHUNKS * 8; i += 256) cnt2[i] = 0;
  }
  int tixA = b * 2, tixB = b * 2 + 1;   // tiles 0..8191
  int eA = tixA >> 10, remA = tixA & 1023, dtA = remA >> 5, htA = remA & 31;
  int eB = tixB >> 10, remB = tixB & 1023, dtB = remB >> 5, htB = remB & 31;
  const float* ibaseA = w1 + ((size_t)eA * D_DIM + dtA * 64) * H_DIM + htA * 64;
  const float* ibaseB = w1 + ((size_t)eB * D_DIM + dtB * 64) * H_DIM + htB * 64;
  int c4 = tid & 15, r0 = tid >> 4;
  float4 va[4], vb[4];
#pragma unroll
  for (int p = 0; p < 4; ++p)
    va[p] = *(const float4*)(ibaseA + (size_t)(r0 + p * 16) * H_DIM + c4 * 4);
#pragma unroll
  for (int p = 0; p < 4; ++p)
    vb[p] = *(const float4*)(ibaseB + (size_t)(r0 + p * 16) * H_DIM + c4 * 4);
#pragma unroll
  for (int p = 0; p < 4; ++p) {
    int rr = r0 + p * 16;
    tile[0][rr][c4 * 4 + 0] = f2bf(va[p].x);
    tile[0][rr][c4 * 4 + 1] = f2bf(va[p].y);
    tile[0][rr][c4 * 4 + 2] = f2bf(va[p].z);
    tile[0][rr][c4 * 4 + 3] = f2bf(va[p].w);
    tile[1][rr][c4 * 4 + 0] = f2bf(vb[p].x);
    tile[1][rr][c4 * 4 + 1] = f2bf(vb[p].y);
    tile[1][rr][c4 * 4 + 2] = f2bf(vb[p].z);
    tile[1][rr][c4 * 4 + 3] = f2bf(vb[p].w);
  }
  __syncthreads();
  int dq = tid & 7, h0 = tid >> 3;
  unsigned short* obaseA = w1t + ((size_t)eA * H_DIM + htA * 64) * D_DIM + dtA * 64;
  unsigned short* obaseB = w1t + ((size_t)eB * H_DIM + htB * 64) * D_DIM + dtB * 64;
#pragma unroll
  for (int tb = 0; tb < 2; ++tb) {
    unsigned short* obase = tb ? obaseB : obaseA;
    unsigned int lo[2][4], hi[2][4];
#pragma unroll
    for (int p = 0; p < 2; ++p) {
      int hh = h0 + p * 32;
#pragma unroll
      for (int u = 0; u < 4; ++u) {
        lo[p][u] = tile[tb][dq * 8 + u * 2][hh];
        hi[p][u] = tile[tb][dq * 8 + u * 2 + 1][hh];
      }
    }
#pragma unroll
    for (int p = 0; p < 2; ++p) {
      int hh = h0 + p * 32;
      uint4 ov = make_uint4(lo[p][0] | (hi[p][0] << 16), lo[p][1] | (hi[p][1] << 16),
                            lo[p][2] | (hi[p][2] << 16), lo[p][3] | (hi[p][3] << 16));
      *(uint4*)(obase + (size_t)hh * D_DIM + dq * 8) = ov;
    }
  }
}

// ---- gating: wg staged in LDS once/block (kills per-warp wg streaming),
//      top-2 + softmax gates + x->bf16 cast + chunk dispatch counts.
//      1024 blocks x 512 threads (8 tokens/block). ----
__global__ __launch_bounds__(512) void gate_kernel(
    const float* __restrict__ x, const float* __restrict__ wg,
    unsigned short* __restrict__ xbf, int* __restrict__ topidx,
    float* __restrict__ gates, int* __restrict__ cnt2)
{
  __shared__ float4 wgl[4096];   // 64 KB: wg [2048][8] fp32
  int tid = threadIdx.x;
  int bx = blockIdx.x;
#pragma unroll
  for (int k = 0; k < 8; ++k) wgl[k * 512 + tid] = ((const float4*)wg)[k * 512 + tid];
  __syncthreads();

  int w = tid >> 6, lane = tid & 63;
  int t = bx * 8 + w;
  const float4* xr = (const float4*)(x + (size_t)t * D_DIM);
  ushort4* xo = (ushort4*)(xbf + (size_t)t * D_DIM);
  float4 v[8];
#pragma unroll
  for (int it = 0; it < 8; ++it) v[it] = xr[it * 64 + lane];
  float acc[8];
#pragma unroll
  for (int e = 0; e < 8; ++e) acc[e] = 0.f;
#pragma unroll
  for (int it = 0; it < 8; ++it) {
    int i4 = it * 64 + lane;
    float xv[4] = {v[it].x, v[it].y, v[it].z, v[it].w};
#pragma unroll
    for (int u = 0; u < 4; ++u) {
      int d = i4 * 4 + u;
      float4 w01 = wgl[d * 2], w23 = wgl[d * 2 + 1];
      acc[0] += xv[u] * w01.x; acc[1] += xv[u] * w01.y;
      acc[2] += xv[u] * w01.z; acc[3] += xv[u] * w01.w;
      acc[4] += xv[u] * w23.x; acc[5] += xv[u] * w23.y;
      acc[6] += xv[u] * w23.z; acc[7] += xv[u] * w23.w;
    }
    ushort4 o;
    o.x = f2bf(v[it].x); o.y = f2bf(v[it].y); o.z = f2bf(v[it].z); o.w = f2bf(v[it].w);
    xo[i4] = o;
  }
#pragma unroll
  for (int off = 1; off < 64; off <<= 1) {
#pragma unroll
    for (int e = 0; e < 8; ++e) acc[e] += __shfl_xor(acc[e], off);
  }
  if (lane == 0) {
    int e1 = 0; float l1 = acc[0];
    for (int e = 1; e < 8; ++e) if (acc[e] > l1) { l1 = acc[e]; e1 = e; }
    int e2 = -1; float l2 = -1e30f;
    for (int e = 0; e < 8; ++e) { if (e == e1) continue; if (acc[e] > l2) { l2 = acc[e]; e2 = e; } }
    float tt = expf(l2 - l1);          // <= 1
    float g1 = 1.f / (1.f + tt);
    float g2 = tt / (1.f + tt);
    topidx[t * 2] = e1; topidx[t * 2 + 1] = e2;
    gates[t * 2] = g1;  gates[t * 2 + 1] = g2;
    int chunk = t >> 8;                // 256 tokens/chunk, 32 chunks
    atomicAdd(&cnt2[(0 * CHUNKS + chunk) * 8 + e1], 1);
    atomicAdd(&cnt2[(1 * CHUNKS + chunk) * 8 + e2], 1);
  }
}

// ---- w2sum[e,h] = sum_d W2[e,h,d]; 2048 blocks, 2 rows/warp ----
__global__ __launch_bounds__(256) void w2sum_kernel(
    const float* __restrict__ w2, float* __restrict__ w2s)
{
  int bx = blockIdx.x;
  int tid = threadIdx.x;
  int wid = tid >> 6, lane = tid & 63;
  int row0 = bx * 8 + wid * 2;
  const float4* rA = (const float4*)(w2 + (size_t)row0 * D_DIM);
  const float4* rB = (const float4*)(w2 + (size_t)(row0 + 1) * D_DIM);
  float4 va[8], vb[8];
#pragma unroll
  for (int i = 0; i < 8; ++i) va[i] = rA[i * 64 + lane];
#pragma unroll
  for (int i = 0; i < 8; ++i) vb[i] = rB[i * 64 + lane];
  float pa = 0.f, pb = 0.f;
#pragma unroll
  for (int i = 0; i < 8; ++i) { pa += va[i].x + va[i].y + va[i].z + va[i].w;
                                pb += vb[i].x + vb[i].y + vb[i].z + vb[i].w; }
#pragma unroll
  for (int off = 1; off < 64; off <<= 1) { pa += __shfl_xor(pa, off); pb += __shfl_xor(pb, off); }
  if (lane == 0) { w2s[row0] = pa; w2s[row0 + 1] = pb; }
}

// ---- misc: b2sum (blocks 0,1) + buffer init (block 2) ----
__global__ __launch_bounds__(256) void misc_kernel(
    const float* __restrict__ b2, float* __restrict__ b2sum,
    int* __restrict__ slot_token, float* __restrict__ s_out,
    unsigned short* __restrict__ xbf)
{
  int b = blockIdx.x, tid = threadIdx.x;
  if (b < 2) {
    int w = tid >> 6, lane = tid & 63;
    int e = b * 4 + w;
    float p = 0.f;
    for (int i = lane; i < D_DIM; i += 64) p += b2[e * D_DIM + i];
#pragma unroll
    for (int off = 1; off < 64; off <<= 1) p += __shfl_xor(p, off);
    if (lane == 0) b2sum[e] = p;
  } else {
    for (int i = tid; i < E_NUM * CAP; i += 256) { s_out[i] = 0.f; slot_token[i] = T_TOK; }
    for (int i = tid; i < D_DIM; i += 256) xbf[(size_t)T_TOK * D_DIM + i] = 0;
  }
}

// ---- scan_small: exclusive scan of cnt2[64 pairs][8] in (j,chunk) order ----
__global__ __launch_bounds__(64) void scan_small_kernel(
    const int* __restrict__ cnt2, int* __restrict__ base,
    int* __restrict__ kept_count)
{
  int lane = threadIdx.x;   // pair index: j*32+chunk
#pragma unroll
  for (int e = 0; e < 8; ++e) {
    int v = cnt2[lane * 8 + e];
    int inc = v;
    for (int off = 1; off < 64; off <<= 1) {
      int o = __shfl_up(inc, off);
      if (lane >= off) inc += o;
    }
    base[lane * 8 + e] = inc - v;
    if (lane == 63) kept_count[e] = min(inc, CAP);
  }
}

// ---- place: stable intra-chunk rank via ballot + cross-wave prefix.
//      32 blocks x 256 threads (1 token/thread). Same GShard order. ----
__global__ __launch_bounds__(256) void place_kernel(
    const int* __restrict__ topidx, const int* __restrict__ base,
    int* __restrict__ slot_token, int* __restrict__ tok_slot)
{
  __shared__ int wcnt[4][8];
  int b = blockIdx.x, tid = threadIdx.x;
  int w = tid >> 6, lane = tid & 63;
  int t = b * 256 + tid;
  unsigned long long lmask = (1ull << lane) - 1ull;

  // ---------- j = 0 ----------
  int ex0 = topidx[t * 2];
  int rank0 = 0;
#pragma unroll
  for (int e = 0; e < 8; ++e) {
    unsigned long long m = __ballot(ex0 == e);
    if (ex0 == e) rank0 = (int)__popcll(m & lmask);
    if (lane == 0) wcnt[w][e] = (int)__popcll(m);
  }
  __syncthreads();
  {
    int pre = 0;
#pragma unroll
    for (int ww = 0; ww < 4; ++ww) if (ww < w) pre += wcnt[ww][ex0];
    int pos = base[(0 * CHUNKS + b) * 8 + ex0] + pre + rank0;
    if (pos < CAP) { tok_slot[t * 2] = ex0 * CAP + pos; slot_token[ex0 * CAP + pos] = t; }
    else tok_slot[t * 2] = -1;
  }
  __syncthreads();
  // ---------- j = 1 ----------
  int ex1 = topidx[t * 2 + 1];
  int rank1 = 0;
#pragma unroll
  for (int e = 0; e < 8; ++e) {
    unsigned long long m = __ballot(ex1 == e);
    if (ex1 == e) rank1 = (int)__popcll(m & lmask);
    if (lane == 0) wcnt[w][e] = (int)__popcll(m);
  }
  __syncthreads();
  {
    int pre = 0;
#pragma unroll
    for (int ww = 0; ww < 4; ++ww) if (ww < w) pre += wcnt[ww][ex1];
    int pos = base[(1 * CHUNKS + b) * 8 + ex1] + pre + rank1;
    if (pos < CAP) { tok_slot[t * 2 + 1] = ex1 * CAP + pos; slot_token[ex1 * CAP + pos] = t; }
    else tok_slot[t * 2 + 1] = -1;
  }
}

// ======================================================================
// 256x256-tile, BK=64, 8-wave (2Mx4N), 8-phase bf16 MFMA GEMM with
// counted-vmcnt pipelining, XOR-swizzled LDS (conflict-free ds_read_b128),
// fused relu + w2sum-dot epilogue.  (unchanged from R2 -> R3)
// ======================================================================
#define FFN_NT 32   // K tiles of 64 over D_DIM=2048

__global__ __launch_bounds__(512, 2) void ffn_kernel(
    const unsigned short* __restrict__ xbf,    // [(T+1)][D] bf16
    const unsigned short* __restrict__ w1t,    // [E][H][D] bf16
    const float* __restrict__ w2s,             // [E][H]
    const float* __restrict__ b1,              // [E][H]
    const int* __restrict__ slot_token,        // [E][CAP]
    const int* __restrict__ kept_count,        // [E]
    float* __restrict__ s_out)                 // [E][CAP]
{
  int bid = blockIdx.x;
  int swz = (bid & 7) * 64 + (bid >> 3);   // bijective XCD swizzle (512 % 8 == 0)
  int e = swz >> 6;
  int rem = swz & 63;
  int mt = rem >> 3, nt = rem & 7;
  if (mt * 256 >= kept_count[e]) return;

  __shared__ unsigned short Asl[4][256 * 32];   // 64 KB
  __shared__ unsigned short Bsl[4][256 * 32];   // 64 KB

  int tid = threadIdx.x;
  int w = tid >> 6, lane = tid & 63;
  int wr = w >> 2, wc = w & 3;                  // 2M x 4N waves
  int l15 = lane & 15, q = lane >> 4;

  // ---- staging source setup (pre-swizzled per-lane global addresses) ----
  int r0s = tid >> 2;                           // rows 0..127 (chunk = 16B)
  int ccs = tid & 3;                            // chunk within 64B row
  int sw0 = (ccs ^ ((r0s >> 1) & 3)) * 8;       // swizzled element offset
  int r1s = r0s + 128;
  int sw1 = (ccs ^ ((r1s >> 1) & 3)) * 8;
  int tokl = slot_token[e * CAP + mt * 256 + r0s];
  int tokh = slot_token[e * CAP + mt * 256 + r1s];
  const unsigned short* gA0 = xbf + (size_t)tokl * D_DIM + sw0;
  const unsigned short* gA1 = xbf + (size_t)tokh * D_DIM + sw1;
  const unsigned short* gB0 = w1t + ((size_t)e * H_DIM + nt * 256 + r0s) * D_DIM + sw0;
  const unsigned short* gB1 = w1t + ((size_t)e * H_DIM + nt * 256 + r1s) * D_DIM + sw1;

  // ---- fragment ds_read addressing (same swizzle) ----
  int rowAa = wr * 128 + l15;
  int rowBb = wc * 64 + l15;
  int offA = rowAa * 32 + (q ^ ((rowAa >> 1) & 3)) * 8;
  int offB = rowBb * 32 + (q ^ ((rowBb >> 1) & 3)) * 8;

  // one STAGE = one half-slab = 2 loads/thread (vmcnt counts 2 per slab)
#define STAGE(SLOT_PTR, G0, G1, KOFS)                                    \
  do {                                                                   \
    async_load16((G0) + (KOFS), (SLOT_PTR) + w * 512);                   \
    async_load16((G1) + (KOFS), (SLOT_PTR) + 4096 + w * 512);            \
  } while (0)

  f32x4 acc[8][4];
#pragma unroll
  for (int i = 0; i < 8; ++i)
#pragma unroll
    for (int j = 0; j < 4; ++j) acc[i][j] = (f32x4)(0.f);

  // ---- prologue: stage (0,A0)(0,B0)(0,A1)(0,B1)(1,A0)(1,B0) ----
  STAGE(&Asl[0][0], gA0, gA1, 0);
  STAGE(&Bsl[0][0], gB0, gB1, 0);
  STAGE(&Asl[1][0], gA0, gA1, 32);
  STAGE(&Bsl[1][0], gB0, gB1, 32);
  STAGE(&Asl[2][0], gA0, gA1, 64);
  STAGE(&Bsl[2][0], gB0, gB1, 64);
  asm volatile("s_waitcnt vmcnt(4)" ::: "memory");   // tile 0 landed, 2 slabs in flight
  __builtin_amdgcn_s_barrier();
  __builtin_amdgcn_sched_barrier(0);

  for (int t = 0; t < FFN_NT; ++t) {
    int d = t & 1;
    const unsigned short* Ak0 = &Asl[d * 2][0];
    const unsigned short* Ak1 = &Asl[d * 2 + 1][0];
    const unsigned short* Bk0 = &Bsl[d * 2][0];
    const unsigned short* Bk1 = &Bsl[d * 2 + 1][0];

    bf16x8 aF[4], bK0[4], bK1[4];

    // ===== phase 0: read A(kh0,m0-3)+B(kh0); stage (t+1,A1); mfma m0-3 kh0 =====
#pragma unroll
    for (int mf = 0; mf < 4; ++mf) aF[mf] = *(const bf16x8*)(Ak0 + offA + mf * 512);
#pragma unroll
    for (int nf = 0; nf < 4; ++nf) bK0[nf] = *(const bf16x8*)(Bk0 + offB + nf * 512);
    if (t < FFN_NT - 1) STAGE(&Asl[(d ^ 1) * 2 + 1][0], gA0, gA1, (t + 1) * 64 + 32);
    __builtin_amdgcn_s_barrier();
    __builtin_amdgcn_sched_barrier(0);
    __builtin_amdgcn_s_setprio(1);
#pragma unroll
    for (int mf = 0; mf < 4; ++mf)
#pragma unroll
      for (int nf = 0; nf < 4; ++nf)
        acc[mf][nf] = __builtin_amdgcn_mfma_f32_16x16x32_bf16(aF[mf], bK0[nf], acc[mf][nf], 0, 0, 0);
    __builtin_amdgcn_s_setprio(0);
    __builtin_amdgcn_s_barrier();
    __builtin_amdgcn_sched_barrier(0);

    // ===== phase 1: read A(kh0,m4-7)+B(kh1); stage (t+1,B1); mfma m4-7 kh0 =====
#pragma unroll
    for (int mf = 0; mf < 4; ++mf) aF[mf] = *(const bf16x8*)(Ak0 + offA + (mf + 4) * 512);
#pragma unroll
    for (int nf = 0; nf < 4; ++nf) bK1[nf] = *(const bf16x8*)(Bk1 + offB + nf * 512);
    if (t < FFN_NT - 1) STAGE(&Bsl[(d ^ 1) * 2 + 1][0], gB0, gB1, (t + 1) * 64 + 32);
    __builtin_amdgcn_s_barrier();
    __builtin_amdgcn_sched_barrier(0);
    __builtin_amdgcn_s_setprio(1);
#pragma unroll
    for (int mf = 0; mf < 4; ++mf)
#pragma unroll
      for (int nf = 0; nf < 4; ++nf)
        acc[mf + 4][nf] = __builtin_amdgcn_mfma_f32_16x16x32_bf16(aF[mf], bK0[nf], acc[mf + 4][nf], 0, 0, 0);
    __builtin_amdgcn_s_setprio(0);
    __builtin_amdgcn_s_barrier();
    __builtin_amdgcn_sched_barrier(0);

    // ===== phase 2: read A(kh1,m0-3); stage (t+2,A0); mfma m0-3 kh1 =====
#pragma unroll
    for (int mf = 0; mf < 4; ++mf) aF[mf] = *(const bf16x8*)(Ak1 + offA + mf * 512);
    if (t < FFN_NT - 2) STAGE(&Asl[d * 2][0], gA0, gA1, (t + 2) * 64);
    __builtin_amdgcn_s_barrier();
    __builtin_amdgcn_sched_barrier(0);
    __builtin_amdgcn_s_setprio(1);
#pragma unroll
    for (int mf = 0; mf < 4; ++mf)
#pragma unroll
      for (int nf = 0; nf < 4; ++nf)
        acc[mf][nf] = __builtin_amdgcn_mfma_f32_16x16x32_bf16(aF[mf], bK1[nf], acc[mf][nf], 0, 0, 0);
    __builtin_amdgcn_s_setprio(0);
    __builtin_amdgcn_s_barrier();
    __builtin_amdgcn_sched_barrier(0);

    // ===== phase 3: read A(kh1,m4-7); stage (t+2,B0); mfma m4-7 kh1; boundary =====
#pragma unroll
    for (int mf = 0; mf < 4; ++mf) aF[mf] = *(const bf16x8*)(Ak1 + offA + (mf + 4) * 512);
    if (t < FFN_NT - 2) STAGE(&Bsl[d * 2][0], gB0, gB1, (t + 2) * 64);
    __builtin_amdgcn_s_barrier();
    __builtin_amdgcn_sched_barrier(0);
    __builtin_amdgcn_s_setprio(1);
#pragma unroll
    for (int mf = 0; mf < 4; ++mf)
#pragma unroll
      for (int nf = 0; nf < 4; ++nf)
        acc[mf + 4][nf] = __builtin_amdgcn_mfma_f32_16x16x32_bf16(aF[mf], bK1[nf], acc[mf + 4][nf], 0, 0, 0);
    __builtin_amdgcn_s_setprio(0);
    if (t < FFN_NT - 2) {
      // tile t+1 fully landed; 2 slabs (t+2,A0)(t+2,B0) stay in flight
      asm volatile("s_waitcnt vmcnt(4)" ::: "memory");
    } else {
      // no further prefetch: drain before the last tile
      asm volatile("s_waitcnt vmcnt(0)" ::: "memory");
    }
    __builtin_amdgcn_s_barrier();
    __builtin_amdgcn_sched_barrier(0);
  }
#undef STAGE

  // ---- epilogue: s[m] = sum_n relu(z + b1[n]) * w2sum[n] ----
  float sp[8][4];
#pragma unroll
  for (int mf = 0; mf < 8; ++mf)
#pragma unroll
    for (int r = 0; r < 4; ++r) sp[mf][r] = 0.f;
#pragma unroll
  for (int nf = 0; nf < 4; ++nf) {
    int n = nt * 256 + wc * 64 + nf * 16 + l15;
    float w2v = w2s[e * H_DIM + n];
    float b1v = b1[e * H_DIM + n];
#pragma unroll
    for (int mf = 0; mf < 8; ++mf)
#pragma unroll
      for (int r = 0; r < 4; ++r) {
        float z = acc[mf][nf][r] + b1v;
        sp[mf][r] += fmaxf(z, 0.f) * w2v;
      }
  }
#pragma unroll
  for (int off = 1; off < 16; off <<= 1)
#pragma unroll
    for (int mf = 0; mf < 8; ++mf)
#pragma unroll
      for (int r = 0; r < 4; ++r) sp[mf][r] += __shfl_xor(sp[mf][r], off);
  if (l15 == 0) {
    int mbase = e * CAP + mt * 256 + wr * 128 + q * 4;
#pragma unroll
    for (int mf = 0; mf < 8; ++mf)
#pragma unroll
      for (int r = 0; r < 4; ++r)
        atomicAdd(&s_out[mbase + mf * 16 + r], sp[mf][r]);
  }
}

// ---------------- combine + per-batch log_softmax ----------------
__global__ __launch_bounds__(1024) void combine_kernel(
    const float* __restrict__ s_in, const int* __restrict__ tok_slot,
    const float* __restrict__ gates, const float* __restrict__ b2sum,
    float* __restrict__ out)
{
  __shared__ float red[1024];
  int b = blockIdx.x, tid = threadIdx.x;
  float y[2];
  float mx = -1e30f;
#pragma unroll
  for (int i = 0; i < 2; ++i) {
    int t = b * 2048 + i * 1024 + tid;
    float accv = 0.f;
#pragma unroll
    for (int j = 0; j < 2; ++j) {
      int sl = tok_slot[t * 2 + j];
      if (sl >= 0) accv += gates[t * 2 + j] * (s_in[sl] + b2sum[sl >> 11]);
    }
    y[i] = accv;
    mx = fmaxf(mx, accv);
  }
  red[tid] = mx; __syncthreads();
  for (int st = 512; st > 0; st >>= 1) {
    if (tid < st) red[tid] = fmaxf(red[tid], red[tid + st]);
    __syncthreads();
  }
  mx = red[0]; __syncthreads();
  float se = 0.f;
#pragma unroll
  for (int i = 0; i < 2; ++i) se += expf(y[i] - mx);
  red[tid] = se; __syncthreads();
  for (int st = 512; st > 0; st >>= 1) {
    if (tid < st) red[tid] += red[tid + st];
    __syncthreads();
  }
  float logZ = mx + logf(red[0]);
#pragma unroll
  for (int i = 0; i < 2; ++i) out[b * 2048 + i * 1024 + tid] = y[i] - logZ;
}

extern "C" void kernel_launch(void* const* d_in, const int* in_sizes, int n_in,
                              void* d_out, int out_size, void* d_ws, size_t ws_size,
                              hipStream_t stream) {
  const float* x  = (const float*)d_in[0];
  const float* wg = (const float*)d_in[1];
  const float* w1 = (const float*)d_in[2];
  const float* b1 = (const float*)d_in[3];
  const float* w2 = (const float*)d_in[4];
  const float* b2 = (const float*)d_in[5];
  float* out = (float*)d_out;

  char* ws = (char*)d_ws;
  size_t off = 0;
  auto alloc = [&](size_t bytes) -> void* {
    void* p = ws + off; off += (bytes + 255) & ~(size_t)255; return p;
  };
  unsigned short* xbf   = (unsigned short*)alloc((size_t)(T_TOK + 1) * D_DIM * 2);
  unsigned short* w1t   = (unsigned short*)alloc((size_t)E_NUM * D_DIM * H_DIM * 2);
  float* w2s            = (float*)alloc((size_t)E_NUM * H_DIM * 4);
  float* gates          = (float*)alloc((size_t)T_TOK * 2 * 4);
  int*   topidx         = (int*)alloc((size_t)T_TOK * 2 * 4);
  int*   tok_slot       = (int*)alloc((size_t)T_TOK * 2 * 4);
  int*   slot_token     = (int*)alloc((size_t)E_NUM * CAP * 4);
  float* s_buf          = (float*)alloc((size_t)E_NUM * CAP * 4);
  float* b2s            = (float*)alloc(256);
  int*   kept           = (int*)alloc(256);
  int*   cnt2           = (int*)alloc((size_t)2 * CHUNKS * 8 * 4);
  int*   basep          = (int*)alloc((size_t)2 * CHUNKS * 8 * 4);

  w1cast_kernel<<<4096, 256, 0, stream>>>(w1, w1t, cnt2);
  gate_kernel<<<1024, 512, 0, stream>>>(x, wg, xbf, topidx, gates, cnt2);
  w2sum_kernel<<<2048, 256, 0, stream>>>(w2, w2s);
  misc_kernel<<<3, 256, 0, stream>>>(b2, b2s, slot_token, s_buf, xbf);
  scan_small_kernel<<<1, 64, 0, stream>>>(cnt2, basep, kept);
  place_kernel<<<CHUNKS, 256, 0, stream>>>(topidx, basep, slot_token, tok_slot);
  ffn_kernel<<<E_NUM * 8 * 8, 512, 0, stream>>>(xbf, w1t, w2s, b1, slot_token, kept, s_buf);
  combine_kernel<<<4, 1024, 0, stream>>>(s_buf, tok_slot, gates, b2s, out);
}